// Round 6
// baseline (415.091 us; speedup 1.0000x reference)
//
#include <hip/hip_runtime.h>
#include <hip/hip_bf16.h>
#include <hip/hip_fp16.h>
#include <math.h>

// Problem constants (from reference)
#define N_NODES 50000
#define N_EDGES 800000
#define N_TOT   (N_EDGES + N_NODES)  // 850000 edges incl. self loops
#define NEG_SLOPE 0.2f

static __device__ __forceinline__ float lrelu(float x){ return x >= 0.f ? x : NEG_SLOPE * x; }

// ---------------- edge dtype detection (int64 vs int32) ----------------
__global__ void k_detect(const int* __restrict__ ei, int* __restrict__ flag){
  if (blockIdx.x == 0 && threadIdx.x == 0){
    int o = 0;
    #pragma unroll
    for (int i = 1; i < 16; i += 2) o |= ei[i];
    *flag = (o == 0) ? 1 : 0;  // 1 => int64 layout
  }
}

// ---------------- CSR build ----------------
__global__ void k_init(int* __restrict__ deg, int* __restrict__ fill){
  int i = blockIdx.x * blockDim.x + threadIdx.x;
  if (i < N_NODES){ deg[i] = 1; fill[i] = 0; }  // deg starts at 1: self loop
}

__global__ void k_count(const int* __restrict__ ei, const int* __restrict__ flag,
                        int* __restrict__ deg){
  int e = blockIdx.x * blockDim.x + threadIdx.x;
  if (e >= N_EDGES) return;
  int f = *flag;
  int d = f ? ei[2*(N_EDGES + e)] : ei[N_EDGES + e];
  atomicAdd(&deg[d], 1);
}

// block-scan: 49 blocks x 1024 elements (256 thr x 4)
__global__ void k_scan1(const int* __restrict__ deg, int* __restrict__ rowptr,
                        int* __restrict__ bsum){
  __shared__ int sd[256];
  int t = threadIdx.x;
  int base = blockIdx.x * 1024 + t * 4;
  int v0 = (base + 0 < N_NODES) ? deg[base + 0] : 0;
  int v1 = (base + 1 < N_NODES) ? deg[base + 1] : 0;
  int v2 = (base + 2 < N_NODES) ? deg[base + 2] : 0;
  int v3 = (base + 3 < N_NODES) ? deg[base + 3] : 0;
  int tsum = v0 + v1 + v2 + v3;
  sd[t] = tsum; __syncthreads();
  for (int off = 1; off < 256; off <<= 1){
    int vv = (t >= off) ? sd[t - off] : 0;
    __syncthreads();
    sd[t] += vv;
    __syncthreads();
  }
  int excl = sd[t] - tsum;
  if (base + 0 < N_NODES) rowptr[base + 0] = excl;
  if (base + 1 < N_NODES) rowptr[base + 1] = excl + v0;
  if (base + 2 < N_NODES) rowptr[base + 2] = excl + v0 + v1;
  if (base + 3 < N_NODES) rowptr[base + 3] = excl + v0 + v1 + v2;
  if (t == 255) bsum[blockIdx.x] = sd[255];
}

#define NB_SCAN 49
__global__ void k_scan2(const int* __restrict__ bsum, int* __restrict__ boff){
  int t = threadIdx.x;  // 64 threads, 1 block
  int v = (t < NB_SCAN) ? bsum[t] : 0;
  int incl = v;
  #pragma unroll
  for (int off = 1; off < 64; off <<= 1){
    int u = __shfl_up(incl, off);
    if (t >= off) incl += u;
  }
  if (t < NB_SCAN) boff[t] = incl - v;
}

__global__ void k_scan3(int* __restrict__ rowptr, const int* __restrict__ boff){
  int i = blockIdx.x * blockDim.x + threadIdx.x;
  if (i < N_NODES) rowptr[i] += boff[i >> 10];
  if (i == 0) rowptr[N_NODES] = N_TOT;
}

__global__ void k_scatter(const int* __restrict__ ei, const int* __restrict__ flag,
                          const int* __restrict__ rowptr, int* __restrict__ fill,
                          int* __restrict__ col){
  int e = blockIdx.x * blockDim.x + threadIdx.x;
  if (e >= N_TOT) return;
  int s, d;
  if (e < N_EDGES){
    int f = *flag;
    if (f){ s = ei[2*e]; d = ei[2*(N_EDGES + e)]; }
    else  { s = ei[e];   d = ei[N_EDGES + e]; }
  } else {
    s = d = e - N_EDGES;   // self loop
  }
  int pos = atomicAdd(&fill[d], 1);
  col[rowptr[d] + pos] = s;
}

// ---------------- feature transforms ----------------
// h is stored as fp16 (halves gather bytes in k_agg); es/ed computed from the
// unrounded f32 accumulators so attention coefficients stay near-exact.

// layer 1: x[N,8] @ W[8,256] -> h[N,256] (fp16); e_src/e_dst[N,4] (f32)
__global__ __launch_bounds__(256) void k_transform1(
    const float* __restrict__ xin, const float* __restrict__ W,
    const float* __restrict__ aS, const float* __restrict__ aD,
    __half* __restrict__ h, float* __restrict__ es, float* __restrict__ ed){
  __shared__ float wl[8 * 256];
  int tid = threadIdx.x;
  for (int i = tid; i < 8 * 256; i += 256) wl[i] = W[i];
  int lane = tid & 63, wv = tid >> 6, head = lane >> 4;
  float4 s4 = *(const float4*)&aS[4 * lane];
  float4 d4 = *(const float4*)&aD[4 * lane];
  __syncthreads();
  int base = (blockIdx.x * 4 + wv) * 8;   // 8 nodes per wave
  for (int m = 0; m < 8; m++){
    int n = base + m;
    if (n >= N_NODES) break;
    float4 xa = *(const float4*)&xin[n * 8];
    float4 xb = *(const float4*)&xin[n * 8 + 4];
    float xs0 = xa.x, xs1 = xa.y, xs2 = xa.z, xs3 = xa.w;
    float xs4 = xb.x, xs5 = xb.y, xs6 = xb.z, xs7 = xb.w;
    float4 acc = make_float4(0.f, 0.f, 0.f, 0.f);
    #define T1STEP(k, xv) { float4 w4 = *(const float4*)&wl[(k)*256 + 4*lane]; \
      acc.x = fmaf(xv, w4.x, acc.x); acc.y = fmaf(xv, w4.y, acc.y); \
      acc.z = fmaf(xv, w4.z, acc.z); acc.w = fmaf(xv, w4.w, acc.w); }
    T1STEP(0, xs0) T1STEP(1, xs1) T1STEP(2, xs2) T1STEP(3, xs3)
    T1STEP(4, xs4) T1STEP(5, xs5) T1STEP(6, xs6) T1STEP(7, xs7)
    #undef T1STEP
    __half2 p0 = __floats2half2_rn(acc.x, acc.y);
    __half2 p1 = __floats2half2_rn(acc.z, acc.w);
    uint2 u; u.x = *(unsigned int*)&p0; u.y = *(unsigned int*)&p1;
    *(uint2*)&h[(size_t)n * 256 + 4 * lane] = u;
    float ps = acc.x*s4.x + acc.y*s4.y + acc.z*s4.z + acc.w*s4.w;
    float pd = acc.x*d4.x + acc.y*d4.y + acc.z*d4.z + acc.w*d4.w;
    #pragma unroll
    for (int off = 1; off < 16; off <<= 1){ ps += __shfl_xor(ps, off); pd += __shfl_xor(pd, off); }
    if ((lane & 15) == 0){ es[n * 4 + head] = ps; ed[n * 4 + head] = pd; }
  }
}

// layer 2: feat[N,64] @ W[64,256] -> h[N,256] (fp16); e_src/e_dst[N,4]
// Two-stage K over a 32 KiB LDS tile (was 64 KiB): occupancy 2 -> 5 blocks/CU.
__global__ __launch_bounds__(256) void k_transform2(
    const float* __restrict__ xin, const float* __restrict__ W,
    const float* __restrict__ aS, const float* __restrict__ aD,
    __half* __restrict__ h, float* __restrict__ es, float* __restrict__ ed){
  __shared__ float wl[32 * 256];   // 32 KiB
  int tid = threadIdx.x;
  int lane = tid & 63, wv = tid >> 6, head = lane >> 4;
  float4 s4 = *(const float4*)&aS[4 * lane];
  float4 d4 = *(const float4*)&aD[4 * lane];
  int base = (blockIdx.x * 4 + wv) * 8;   // 8 nodes per wave
  float xr[8];
  #pragma unroll
  for (int m = 0; m < 8; m++){
    int n = base + m;
    xr[m] = (n < N_NODES) ? xin[(size_t)n * 64 + lane] : 0.f;
  }
  float4 acc[8];
  #pragma unroll
  for (int m = 0; m < 8; m++) acc[m] = make_float4(0.f, 0.f, 0.f, 0.f);
  for (int hf = 0; hf < 2; hf++){
    if (hf) __syncthreads();   // all reads of previous half done
    const float4* Wv = (const float4*)(W + hf * 32 * 256);
    float4* wlv = (float4*)wl;
    #pragma unroll
    for (int i = 0; i < 8; i++) wlv[tid + 256 * i] = Wv[tid + 256 * i];
    __syncthreads();
    #pragma unroll 4
    for (int k = 0; k < 32; k++){
      float4 w4 = *(const float4*)&wl[k * 256 + 4 * lane];
      #pragma unroll
      for (int m = 0; m < 8; m++){
        float xv = __shfl(xr[m], hf * 32 + k);
        acc[m].x = fmaf(xv, w4.x, acc[m].x);
        acc[m].y = fmaf(xv, w4.y, acc[m].y);
        acc[m].z = fmaf(xv, w4.z, acc[m].z);
        acc[m].w = fmaf(xv, w4.w, acc[m].w);
      }
    }
  }
  #pragma unroll
  for (int m = 0; m < 8; m++){
    int n = base + m;
    if (n >= N_NODES) break;
    __half2 p0 = __floats2half2_rn(acc[m].x, acc[m].y);
    __half2 p1 = __floats2half2_rn(acc[m].z, acc[m].w);
    uint2 u; u.x = *(unsigned int*)&p0; u.y = *(unsigned int*)&p1;
    *(uint2*)&h[(size_t)n * 256 + 4 * lane] = u;
    float ps = acc[m].x*s4.x + acc[m].y*s4.y + acc[m].z*s4.z + acc[m].w*s4.w;
    float pd = acc[m].x*d4.x + acc[m].y*d4.y + acc[m].z*d4.z + acc[m].w*d4.w;
    #pragma unroll
    for (int off = 1; off < 16; off <<= 1){ ps += __shfl_xor(ps, off); pd += __shfl_xor(pd, off); }
    if ((lane & 15) == 0){ es[n * 4 + head] = ps; ed[n * 4 + head] = pd; }
  }
}

// layer 3: feat[N,64] @ W3[64,1] -> h3[N]; e3 = h3 * a
__global__ __launch_bounds__(256) void k_transform3(
    const float* __restrict__ xin, const float* __restrict__ W3,
    const float* __restrict__ aS, const float* __restrict__ aD,
    float* __restrict__ h3, float* __restrict__ es3, float* __restrict__ ed3){
  int gid = blockIdx.x * blockDim.x + threadIdx.x;
  int n = gid >> 6, lane = gid & 63;
  if (n >= N_NODES) return;
  float v = xin[(size_t)n * 64 + lane] * W3[lane];
  #pragma unroll
  for (int off = 1; off < 64; off <<= 1) v += __shfl_xor(v, off);
  if (lane == 0){
    h3[n] = v;
    es3[n] = v * aS[0];
    ed3[n] = v * aD[0];
  }
}

// ---------------- aggregation (layers 1,2): one wave per dst node ----------------
// No-max softmax (logits O(1-5) analytically; shift-invariant => identical math).
// 16-edge blocks: phase A computes all 16x4 (edge,head) weights ONCE (not x16
// redundantly); phase B broadcasts s via readlane (uniform idx -> SGPR/saddr)
// and w via one bpermute (LDS pipe, off the VALU).
__global__ __launch_bounds__(256) void k_agg(
    const __half* __restrict__ h, const float* __restrict__ es, const float* __restrict__ ed,
    const int* __restrict__ rowptr, const int* __restrict__ col,
    const float* __restrict__ bias, float* __restrict__ outf){
  int gid = blockIdx.x * blockDim.x + threadIdx.x;
  int d = gid >> 6, lane = gid & 63;
  if (d >= N_NODES) return;
  int start = rowptr[d], end = rowptr[d + 1];
  int head = lane >> 4, e16 = lane & 15;
  float edh = ed[d * 4 + head];
  const __half* hp = h + 4 * lane;
  float4 acc = make_float4(0.f, 0.f, 0.f, 0.f);
  float wsum = 0.f;
  for (int base = start; base < end; base += 16){
    int nb = end - base; nb = nb < 16 ? nb : 16;
    // phase A: weights for 16 edges x 4 heads, one lane each
    int s_mine = col[base + (e16 < nb ? e16 : 0)];
    float lg = lrelu(es[s_mine * 4 + head] + edh);
    float w_mine = (e16 < nb) ? __expf(lg) : 0.f;
    float ws = w_mine;
    ws += __shfl_xor(ws, 1); ws += __shfl_xor(ws, 2);
    ws += __shfl_xor(ws, 4); ws += __shfl_xor(ws, 8);
    wsum += ws;                               // per-head block sum
    // phase B: gather h rows, weight via bpermute broadcast
    #pragma unroll 4
    for (int e = 0; e < nb; e++){
      int s_e = __shfl(s_mine, e);            // uniform idx -> readlane -> SGPR
      float w_e = __shfl(w_mine, (head << 4) | e);  // per-lane idx -> bpermute
      uint2 u = *(const uint2*)(hp + (size_t)s_e * 256);
      float2 a = __half22float2(*(__half2*)&u.x);
      float2 b = __half22float2(*(__half2*)&u.y);
      acc.x = fmaf(w_e, a.x, acc.x); acc.y = fmaf(w_e, a.y, acc.y);
      acc.z = fmaf(w_e, b.x, acc.z); acc.w = fmaf(w_e, b.y, acc.w);
    }
  }
  float inv = 1.0f / (wsum + 1e-16f);
  acc.x *= inv; acc.y *= inv; acc.z *= inv; acc.w *= inv;
  // mean over heads: sum lanes differing in bits 4,5
  #pragma unroll
  for (int off = 16; off < 64; off <<= 1){
    acc.x += __shfl_xor(acc.x, off);
    acc.y += __shfl_xor(acc.y, off);
    acc.z += __shfl_xor(acc.z, off);
    acc.w += __shfl_xor(acc.w, off);
  }
  if (lane < 16){
    float4 b4 = *(const float4*)&bias[4 * lane];
    float ox = 0.25f * acc.x + b4.x;
    float oy = 0.25f * acc.y + b4.y;
    float oz = 0.25f * acc.z + b4.z;
    float ow = 0.25f * acc.w + b4.w;
    ox = ox > 0.f ? ox : expm1f(ox);   // ELU
    oy = oy > 0.f ? oy : expm1f(oy);
    oz = oz > 0.f ? oz : expm1f(oz);
    ow = ow > 0.f ? ow : expm1f(ow);
    float4 o = make_float4(ox, oy, oz, ow);
    *(float4*)&outf[(size_t)d * 64 + 4 * lane] = o;
  }
}

// ---------------- aggregation layer 3 (1 head, 1 channel) + sigmoid ----------------
// 4 nodes per wave, 16 lanes each (avg degree ~17 => good lane utilization).
__global__ __launch_bounds__(256) void k_agg3(
    const float* __restrict__ h3, const float* __restrict__ es3, const float* __restrict__ ed3,
    const int* __restrict__ rowptr, const int* __restrict__ col,
    const float* __restrict__ b3, float* __restrict__ out){
  int gid = blockIdx.x * blockDim.x + threadIdx.x;
  int wv = gid >> 6, lane = gid & 63;
  int sub = lane >> 4, li = lane & 15;
  int d = wv * 4 + sub;
  if (d < N_NODES){
    int start = rowptr[d], end = rowptr[d + 1];
    float edv = ed3[d];
    float num = 0.f, den = 0.f;
    for (int i = start + li; i < end; i += 16){
      int s = col[i];
      float wgt = __expf(lrelu(es3[s] + edv));   // no-max softmax
      den += wgt;
      num = fmaf(wgt, h3[s], num);
    }
    #pragma unroll
    for (int off = 1; off < 16; off <<= 1){
      num += __shfl_xor(num, off);
      den += __shfl_xor(den, off);
    }
    if (li == 0){
      float v = num / (den + 1e-16f) + b3[0];
      out[d] = 1.f / (1.f + __expf(-v));
    }
  }
}

// ---------------- launcher ----------------
extern "C" void kernel_launch(void* const* d_in, const int* in_sizes, int n_in,
                              void* d_out, int out_size, void* d_ws, size_t ws_size,
                              hipStream_t stream) {
  const float* x   = (const float*)d_in[0];
  const int*   ei  = (const int*)  d_in[1];
  const float* W1  = (const float*)d_in[2];
  const float* b1  = (const float*)d_in[3];
  const float* as1 = (const float*)d_in[4];
  const float* ad1 = (const float*)d_in[5];
  const float* W2  = (const float*)d_in[6];
  const float* b2  = (const float*)d_in[7];
  const float* as2 = (const float*)d_in[8];
  const float* ad2 = (const float*)d_in[9];
  const float* W3  = (const float*)d_in[10];
  const float* b3  = (const float*)d_in[11];
  const float* as3 = (const float*)d_in[12];
  const float* ad3 = (const float*)d_in[13];
  float* out = (float*)d_out;

  // workspace layout (all offsets 256B-aligned)
  char* w = (char*)d_ws;
  size_t off = 0;
  auto alloc = [&](size_t bytes) -> char* {
    char* p = w + off;
    off += (bytes + 255) & ~size_t(255);
    return p;
  };
  int*    flag   = (int*)   alloc(64);
  int*    deg    = (int*)   alloc(N_NODES * 4);
  int*    fill   = (int*)   alloc(N_NODES * 4);
  int*    rowptr = (int*)   alloc((N_NODES + 1) * 4);
  int*    bsum   = (int*)   alloc(64 * 4);
  int*    boff   = (int*)   alloc(64 * 4);
  int*    col    = (int*)   alloc((size_t)N_TOT * 4);
  __half* h      = (__half*)alloc((size_t)N_NODES * 256 * 2);  // 25.6 MB fp16
  float*  es     = (float*) alloc((size_t)N_NODES * 4 * 4);
  float*  ed     = (float*) alloc((size_t)N_NODES * 4 * 4);
  float*  feat1  = (float*) alloc((size_t)N_NODES * 64 * 4);   // 12.8 MB
  float*  feat2  = (float*) alloc((size_t)N_NODES * 64 * 4);   // 12.8 MB
  float*  h3     = (float*) alloc(N_NODES * 4);
  float*  es3    = (float*) alloc(N_NODES * 4);
  float*  ed3    = (float*) alloc(N_NODES * 4);
  (void)ws_size; (void)in_sizes; (void)n_in; (void)out_size;

  // ---- CSR build (identical for all 3 layers) ----
  k_detect <<<1, 64, 0, stream>>>(ei, flag);
  k_init   <<<(N_NODES + 255) / 256, 256, 0, stream>>>(deg, fill);
  k_count  <<<(N_EDGES + 255) / 256, 256, 0, stream>>>(ei, flag, deg);
  k_scan1  <<<NB_SCAN, 256, 0, stream>>>(deg, rowptr, bsum);
  k_scan2  <<<1, 64, 0, stream>>>(bsum, boff);
  k_scan3  <<<(N_NODES + 255) / 256, 256, 0, stream>>>(rowptr, boff);
  k_scatter<<<(N_TOT + 255) / 256, 256, 0, stream>>>(ei, flag, rowptr, fill, col);

  const int grid_t12 = (N_NODES + 31) / 32;        // 8 nodes/wave * 4 waves
  const int grid_wpn = (N_NODES * 64 + 255) / 256; // wave per node
  const int grid_w4n = ((N_NODES + 3) / 4 * 64 + 255) / 256; // 4 nodes per wave

  // ---- layer 1 ----
  k_transform1<<<grid_t12, 256, 0, stream>>>(x, W1, as1, ad1, h, es, ed);
  k_agg       <<<grid_wpn, 256, 0, stream>>>(h, es, ed, rowptr, col, b1, feat1);
  // ---- layer 2 ----
  k_transform2<<<grid_t12, 256, 0, stream>>>(feat1, W2, as2, ad2, h, es, ed);
  k_agg       <<<grid_wpn, 256, 0, stream>>>(h, es, ed, rowptr, col, b2, feat2);
  // ---- layer 3 ----
  k_transform3<<<grid_wpn, 256, 0, stream>>>(feat2, W3, as3, ad3, h3, es3, ed3);
  k_agg3      <<<grid_w4n, 256, 0, stream>>>(h3, es3, ed3, rowptr, col, b3, out);
}

// Round 7
// 392.848 us; speedup vs baseline: 1.0566x; 1.0566x over previous
//
#include <hip/hip_runtime.h>
#include <hip/hip_bf16.h>
#include <hip/hip_fp16.h>
#include <math.h>

// Problem constants (from reference)
#define N_NODES 50000
#define N_EDGES 800000
#define N_TOT   (N_EDGES + N_NODES)  // 850000 edges incl. self loops
#define NEG_SLOPE 0.2f

static __device__ __forceinline__ float lrelu(float x){ return x >= 0.f ? x : NEG_SLOPE * x; }

// ---------------- edge dtype detection (int64 vs int32) ----------------
__global__ void k_detect(const int* __restrict__ ei, int* __restrict__ flag){
  if (blockIdx.x == 0 && threadIdx.x == 0){
    int o = 0;
    #pragma unroll
    for (int i = 1; i < 16; i += 2) o |= ei[i];
    *flag = (o == 0) ? 1 : 0;  // 1 => int64 layout
  }
}

// ---------------- CSR build ----------------
__global__ void k_init(int* __restrict__ deg, int* __restrict__ fill){
  int i = blockIdx.x * blockDim.x + threadIdx.x;
  if (i < N_NODES){ deg[i] = 1; fill[i] = 0; }  // deg starts at 1: self loop
}

__global__ void k_count(const int* __restrict__ ei, const int* __restrict__ flag,
                        int* __restrict__ deg){
  int e = blockIdx.x * blockDim.x + threadIdx.x;
  if (e >= N_EDGES) return;
  int f = *flag;
  int d = f ? ei[2*(N_EDGES + e)] : ei[N_EDGES + e];
  atomicAdd(&deg[d], 1);
}

// block-scan: 49 blocks x 1024 elements (256 thr x 4)
__global__ void k_scan1(const int* __restrict__ deg, int* __restrict__ rowptr,
                        int* __restrict__ bsum){
  __shared__ int sd[256];
  int t = threadIdx.x;
  int base = blockIdx.x * 1024 + t * 4;
  int v0 = (base + 0 < N_NODES) ? deg[base + 0] : 0;
  int v1 = (base + 1 < N_NODES) ? deg[base + 1] : 0;
  int v2 = (base + 2 < N_NODES) ? deg[base + 2] : 0;
  int v3 = (base + 3 < N_NODES) ? deg[base + 3] : 0;
  int tsum = v0 + v1 + v2 + v3;
  sd[t] = tsum; __syncthreads();
  for (int off = 1; off < 256; off <<= 1){
    int vv = (t >= off) ? sd[t - off] : 0;
    __syncthreads();
    sd[t] += vv;
    __syncthreads();
  }
  int excl = sd[t] - tsum;
  if (base + 0 < N_NODES) rowptr[base + 0] = excl;
  if (base + 1 < N_NODES) rowptr[base + 1] = excl + v0;
  if (base + 2 < N_NODES) rowptr[base + 2] = excl + v0 + v1;
  if (base + 3 < N_NODES) rowptr[base + 3] = excl + v0 + v1 + v2;
  if (t == 255) bsum[blockIdx.x] = sd[255];
}

#define NB_SCAN 49
__global__ void k_scan2(const int* __restrict__ bsum, int* __restrict__ boff){
  int t = threadIdx.x;  // 64 threads, 1 block
  int v = (t < NB_SCAN) ? bsum[t] : 0;
  int incl = v;
  #pragma unroll
  for (int off = 1; off < 64; off <<= 1){
    int u = __shfl_up(incl, off);
    if (t >= off) incl += u;
  }
  if (t < NB_SCAN) boff[t] = incl - v;
}

__global__ void k_scan3(int* __restrict__ rowptr, const int* __restrict__ boff){
  int i = blockIdx.x * blockDim.x + threadIdx.x;
  if (i < N_NODES) rowptr[i] += boff[i >> 10];
  if (i == 0) rowptr[N_NODES] = N_TOT;
}

__global__ void k_scatter(const int* __restrict__ ei, const int* __restrict__ flag,
                          const int* __restrict__ rowptr, int* __restrict__ fill,
                          int* __restrict__ col){
  int e = blockIdx.x * blockDim.x + threadIdx.x;
  if (e >= N_TOT) return;
  int s, d;
  if (e < N_EDGES){
    int f = *flag;
    if (f){ s = ei[2*e]; d = ei[2*(N_EDGES + e)]; }
    else  { s = ei[e];   d = ei[N_EDGES + e]; }
  } else {
    s = d = e - N_EDGES;   // self loop
  }
  int pos = atomicAdd(&fill[d], 1);
  col[rowptr[d] + pos] = s;
}

// ---------------- feature transforms ----------------
// h is stored as fp16 (halves gather bytes in k_agg); es/ed computed from the
// unrounded f32 accumulators so attention coefficients stay near-exact.

// layer 1: x[N,8] @ W[8,256] -> h[N,256] (fp16); e_src/e_dst[N,4] (f32)
__global__ __launch_bounds__(256) void k_transform1(
    const float* __restrict__ xin, const float* __restrict__ W,
    const float* __restrict__ aS, const float* __restrict__ aD,
    __half* __restrict__ h, float* __restrict__ es, float* __restrict__ ed){
  __shared__ float wl[8 * 256];
  int tid = threadIdx.x;
  for (int i = tid; i < 8 * 256; i += 256) wl[i] = W[i];
  int lane = tid & 63, wv = tid >> 6, head = lane >> 4;
  float4 s4 = *(const float4*)&aS[4 * lane];
  float4 d4 = *(const float4*)&aD[4 * lane];
  __syncthreads();
  int base = (blockIdx.x * 4 + wv) * 8;   // 8 nodes per wave
  for (int m = 0; m < 8; m++){
    int n = base + m;
    if (n >= N_NODES) break;
    float4 xa = *(const float4*)&xin[n * 8];
    float4 xb = *(const float4*)&xin[n * 8 + 4];
    float xs0 = xa.x, xs1 = xa.y, xs2 = xa.z, xs3 = xa.w;
    float xs4 = xb.x, xs5 = xb.y, xs6 = xb.z, xs7 = xb.w;
    float4 acc = make_float4(0.f, 0.f, 0.f, 0.f);
    #define T1STEP(k, xv) { float4 w4 = *(const float4*)&wl[(k)*256 + 4*lane]; \
      acc.x = fmaf(xv, w4.x, acc.x); acc.y = fmaf(xv, w4.y, acc.y); \
      acc.z = fmaf(xv, w4.z, acc.z); acc.w = fmaf(xv, w4.w, acc.w); }
    T1STEP(0, xs0) T1STEP(1, xs1) T1STEP(2, xs2) T1STEP(3, xs3)
    T1STEP(4, xs4) T1STEP(5, xs5) T1STEP(6, xs6) T1STEP(7, xs7)
    #undef T1STEP
    __half2 p0 = __floats2half2_rn(acc.x, acc.y);
    __half2 p1 = __floats2half2_rn(acc.z, acc.w);
    uint2 u; u.x = *(unsigned int*)&p0; u.y = *(unsigned int*)&p1;
    *(uint2*)&h[(size_t)n * 256 + 4 * lane] = u;
    float ps = acc.x*s4.x + acc.y*s4.y + acc.z*s4.z + acc.w*s4.w;
    float pd = acc.x*d4.x + acc.y*d4.y + acc.z*d4.z + acc.w*d4.w;
    #pragma unroll
    for (int off = 1; off < 16; off <<= 1){ ps += __shfl_xor(ps, off); pd += __shfl_xor(pd, off); }
    if ((lane & 15) == 0){ es[n * 4 + head] = ps; ed[n * 4 + head] = pd; }
  }
}

// layer 2: feat[N,64] @ W[64,256] -> h[N,256] (fp16); e_src/e_dst[N,4]
// Two-stage K over a 32 KiB LDS tile: occupancy 2 -> ~5 blocks/CU.
__global__ __launch_bounds__(256) void k_transform2(
    const float* __restrict__ xin, const float* __restrict__ W,
    const float* __restrict__ aS, const float* __restrict__ aD,
    __half* __restrict__ h, float* __restrict__ es, float* __restrict__ ed){
  __shared__ float wl[32 * 256];   // 32 KiB
  int tid = threadIdx.x;
  int lane = tid & 63, wv = tid >> 6, head = lane >> 4;
  float4 s4 = *(const float4*)&aS[4 * lane];
  float4 d4 = *(const float4*)&aD[4 * lane];
  int base = (blockIdx.x * 4 + wv) * 8;   // 8 nodes per wave
  float xr[8];
  #pragma unroll
  for (int m = 0; m < 8; m++){
    int n = base + m;
    xr[m] = (n < N_NODES) ? xin[(size_t)n * 64 + lane] : 0.f;
  }
  float4 acc[8];
  #pragma unroll
  for (int m = 0; m < 8; m++) acc[m] = make_float4(0.f, 0.f, 0.f, 0.f);
  for (int hf = 0; hf < 2; hf++){
    if (hf) __syncthreads();   // all reads of previous half done
    const float4* Wv = (const float4*)(W + hf * 32 * 256);
    float4* wlv = (float4*)wl;
    #pragma unroll
    for (int i = 0; i < 8; i++) wlv[tid + 256 * i] = Wv[tid + 256 * i];
    __syncthreads();
    #pragma unroll 4
    for (int k = 0; k < 32; k++){
      float4 w4 = *(const float4*)&wl[k * 256 + 4 * lane];
      #pragma unroll
      for (int m = 0; m < 8; m++){
        float xv = __shfl(xr[m], hf * 32 + k);
        acc[m].x = fmaf(xv, w4.x, acc[m].x);
        acc[m].y = fmaf(xv, w4.y, acc[m].y);
        acc[m].z = fmaf(xv, w4.z, acc[m].z);
        acc[m].w = fmaf(xv, w4.w, acc[m].w);
      }
    }
  }
  #pragma unroll
  for (int m = 0; m < 8; m++){
    int n = base + m;
    if (n >= N_NODES) break;
    __half2 p0 = __floats2half2_rn(acc[m].x, acc[m].y);
    __half2 p1 = __floats2half2_rn(acc[m].z, acc[m].w);
    uint2 u; u.x = *(unsigned int*)&p0; u.y = *(unsigned int*)&p1;
    *(uint2*)&h[(size_t)n * 256 + 4 * lane] = u;
    float ps = acc[m].x*s4.x + acc[m].y*s4.y + acc[m].z*s4.z + acc[m].w*s4.w;
    float pd = acc[m].x*d4.x + acc[m].y*d4.y + acc[m].z*d4.z + acc[m].w*d4.w;
    #pragma unroll
    for (int off = 1; off < 16; off <<= 1){ ps += __shfl_xor(ps, off); pd += __shfl_xor(pd, off); }
    if ((lane & 15) == 0){ es[n * 4 + head] = ps; ed[n * 4 + head] = pd; }
  }
}

// layer 3: feat[N,64] @ W3[64,1] -> h3[N]; e3 = h3 * a
__global__ __launch_bounds__(256) void k_transform3(
    const float* __restrict__ xin, const float* __restrict__ W3,
    const float* __restrict__ aS, const float* __restrict__ aD,
    float* __restrict__ h3, float* __restrict__ es3, float* __restrict__ ed3){
  int gid = blockIdx.x * blockDim.x + threadIdx.x;
  int n = gid >> 6, lane = gid & 63;
  if (n >= N_NODES) return;
  float v = xin[(size_t)n * 64 + lane] * W3[lane];
  #pragma unroll
  for (int off = 1; off < 64; off <<= 1) v += __shfl_xor(v, off);
  if (lane == 0){
    h3[n] = v;
    es3[n] = v * aS[0];
    ed3[n] = v * aD[0];
  }
}

// ---------------- aggregation (layers 1,2): one wave per dst node ----------------
// No-max softmax (logits O(1-5) analytically; shift-invariant => identical math).
// R5 dataflow (per-lane redundant weight compute — VALU has slack) with 4-way
// unroll: 4 col loads then 4 independent 1KB h-gathers + 4 es loads issued
// before any consume => 4 gathers in flight per wave (latency-limited regime).
__global__ __launch_bounds__(256) void k_agg(
    const __half* __restrict__ h, const float* __restrict__ es, const float* __restrict__ ed,
    const int* __restrict__ rowptr, const int* __restrict__ col,
    const float* __restrict__ bias, float* __restrict__ outf){
  int gid = blockIdx.x * blockDim.x + threadIdx.x;
  int d = gid >> 6, lane = gid & 63;
  if (d >= N_NODES) return;
  int start = rowptr[d], end = rowptr[d + 1];
  int head = lane >> 4;
  float eh = ed[d * 4 + head];          // 4 distinct addrs per wave, L2-hot
  const __half* hp = h + 4 * lane;
  float4 acc = make_float4(0.f, 0.f, 0.f, 0.f);
  float wsum = 0.f;
  int i = start;
  for (; i + 4 <= end; i += 4){
    int s0 = col[i], s1 = col[i + 1], s2 = col[i + 2], s3 = col[i + 3];
    uint2 u0 = *(const uint2*)(hp + (size_t)s0 * 256);
    uint2 u1 = *(const uint2*)(hp + (size_t)s1 * 256);
    uint2 u2 = *(const uint2*)(hp + (size_t)s2 * 256);
    uint2 u3 = *(const uint2*)(hp + (size_t)s3 * 256);
    float e0 = es[s0 * 4 + head], e1 = es[s1 * 4 + head];
    float e2 = es[s2 * 4 + head], e3 = es[s3 * 4 + head];
    float w0 = __expf(lrelu(e0 + eh));
    float w1 = __expf(lrelu(e1 + eh));
    float w2 = __expf(lrelu(e2 + eh));
    float w3 = __expf(lrelu(e3 + eh));
    wsum += (w0 + w1) + (w2 + w3);
    float2 a0 = __half22float2(*(__half2*)&u0.x), b0 = __half22float2(*(__half2*)&u0.y);
    float2 a1 = __half22float2(*(__half2*)&u1.x), b1 = __half22float2(*(__half2*)&u1.y);
    float2 a2 = __half22float2(*(__half2*)&u2.x), b2 = __half22float2(*(__half2*)&u2.y);
    float2 a3 = __half22float2(*(__half2*)&u3.x), b3 = __half22float2(*(__half2*)&u3.y);
    acc.x = fmaf(w0, a0.x, acc.x); acc.y = fmaf(w0, a0.y, acc.y);
    acc.z = fmaf(w0, b0.x, acc.z); acc.w = fmaf(w0, b0.y, acc.w);
    acc.x = fmaf(w1, a1.x, acc.x); acc.y = fmaf(w1, a1.y, acc.y);
    acc.z = fmaf(w1, b1.x, acc.z); acc.w = fmaf(w1, b1.y, acc.w);
    acc.x = fmaf(w2, a2.x, acc.x); acc.y = fmaf(w2, a2.y, acc.y);
    acc.z = fmaf(w2, b2.x, acc.z); acc.w = fmaf(w2, b2.y, acc.w);
    acc.x = fmaf(w3, a3.x, acc.x); acc.y = fmaf(w3, a3.y, acc.y);
    acc.z = fmaf(w3, b3.x, acc.z); acc.w = fmaf(w3, b3.y, acc.w);
  }
  for (; i < end; i++){
    int s0 = col[i];
    uint2 u0 = *(const uint2*)(hp + (size_t)s0 * 256);
    float w0 = __expf(lrelu(es[s0 * 4 + head] + eh));
    wsum += w0;
    float2 a0 = __half22float2(*(__half2*)&u0.x), b0 = __half22float2(*(__half2*)&u0.y);
    acc.x = fmaf(w0, a0.x, acc.x); acc.y = fmaf(w0, a0.y, acc.y);
    acc.z = fmaf(w0, b0.x, acc.z); acc.w = fmaf(w0, b0.y, acc.w);
  }
  float inv = 1.0f / (wsum + 1e-16f);
  acc.x *= inv; acc.y *= inv; acc.z *= inv; acc.w *= inv;
  // mean over heads: sum lanes differing in bits 4,5
  #pragma unroll
  for (int off = 16; off < 64; off <<= 1){
    acc.x += __shfl_xor(acc.x, off);
    acc.y += __shfl_xor(acc.y, off);
    acc.z += __shfl_xor(acc.z, off);
    acc.w += __shfl_xor(acc.w, off);
  }
  if (lane < 16){
    float4 b4 = *(const float4*)&bias[4 * lane];
    float ox = 0.25f * acc.x + b4.x;
    float oy = 0.25f * acc.y + b4.y;
    float oz = 0.25f * acc.z + b4.z;
    float ow = 0.25f * acc.w + b4.w;
    ox = ox > 0.f ? ox : expm1f(ox);   // ELU
    oy = oy > 0.f ? oy : expm1f(oy);
    oz = oz > 0.f ? oz : expm1f(oz);
    ow = ow > 0.f ? ow : expm1f(ow);
    float4 o = make_float4(ox, oy, oz, ow);
    *(float4*)&outf[(size_t)d * 64 + 4 * lane] = o;
  }
}

// ---------------- aggregation layer 3 (1 head, 1 channel) + sigmoid ----------------
// 4 nodes per wave, 16 lanes each (avg degree ~17 => good lane utilization).
__global__ __launch_bounds__(256) void k_agg3(
    const float* __restrict__ h3, const float* __restrict__ es3, const float* __restrict__ ed3,
    const int* __restrict__ rowptr, const int* __restrict__ col,
    const float* __restrict__ b3, float* __restrict__ out){
  int gid = blockIdx.x * blockDim.x + threadIdx.x;
  int wv = gid >> 6, lane = gid & 63;
  int sub = lane >> 4, li = lane & 15;
  int d = wv * 4 + sub;
  if (d < N_NODES){
    int start = rowptr[d], end = rowptr[d + 1];
    float edv = ed3[d];
    float num = 0.f, den = 0.f;
    for (int i = start + li; i < end; i += 16){
      int s = col[i];
      float wgt = __expf(lrelu(es3[s] + edv));   // no-max softmax
      den += wgt;
      num = fmaf(wgt, h3[s], num);
    }
    #pragma unroll
    for (int off = 1; off < 16; off <<= 1){
      num += __shfl_xor(num, off);
      den += __shfl_xor(den, off);
    }
    if (li == 0){
      float v = num / (den + 1e-16f) + b3[0];
      out[d] = 1.f / (1.f + __expf(-v));
    }
  }
}

// ---------------- launcher ----------------
extern "C" void kernel_launch(void* const* d_in, const int* in_sizes, int n_in,
                              void* d_out, int out_size, void* d_ws, size_t ws_size,
                              hipStream_t stream) {
  const float* x   = (const float*)d_in[0];
  const int*   ei  = (const int*)  d_in[1];
  const float* W1  = (const float*)d_in[2];
  const float* b1  = (const float*)d_in[3];
  const float* as1 = (const float*)d_in[4];
  const float* ad1 = (const float*)d_in[5];
  const float* W2  = (const float*)d_in[6];
  const float* b2  = (const float*)d_in[7];
  const float* as2 = (const float*)d_in[8];
  const float* ad2 = (const float*)d_in[9];
  const float* W3  = (const float*)d_in[10];
  const float* b3  = (const float*)d_in[11];
  const float* as3 = (const float*)d_in[12];
  const float* ad3 = (const float*)d_in[13];
  float* out = (float*)d_out;

  // workspace layout (all offsets 256B-aligned)
  char* w = (char*)d_ws;
  size_t off = 0;
  auto alloc = [&](size_t bytes) -> char* {
    char* p = w + off;
    off += (bytes + 255) & ~size_t(255);
    return p;
  };
  int*    flag   = (int*)   alloc(64);
  int*    deg    = (int*)   alloc(N_NODES * 4);
  int*    fill   = (int*)   alloc(N_NODES * 4);
  int*    rowptr = (int*)   alloc((N_NODES + 1) * 4);
  int*    bsum   = (int*)   alloc(64 * 4);
  int*    boff   = (int*)   alloc(64 * 4);
  int*    col    = (int*)   alloc((size_t)N_TOT * 4);
  __half* h      = (__half*)alloc((size_t)N_NODES * 256 * 2);  // 25.6 MB fp16
  float*  es     = (float*) alloc((size_t)N_NODES * 4 * 4);
  float*  ed     = (float*) alloc((size_t)N_NODES * 4 * 4);
  float*  feat1  = (float*) alloc((size_t)N_NODES * 64 * 4);   // 12.8 MB
  float*  feat2  = (float*) alloc((size_t)N_NODES * 64 * 4);   // 12.8 MB
  float*  h3     = (float*) alloc(N_NODES * 4);
  float*  es3    = (float*) alloc(N_NODES * 4);
  float*  ed3    = (float*) alloc(N_NODES * 4);
  (void)ws_size; (void)in_sizes; (void)n_in; (void)out_size;

  // ---- CSR build (identical for all 3 layers) ----
  k_detect <<<1, 64, 0, stream>>>(ei, flag);
  k_init   <<<(N_NODES + 255) / 256, 256, 0, stream>>>(deg, fill);
  k_count  <<<(N_EDGES + 255) / 256, 256, 0, stream>>>(ei, flag, deg);
  k_scan1  <<<NB_SCAN, 256, 0, stream>>>(deg, rowptr, bsum);
  k_scan2  <<<1, 64, 0, stream>>>(bsum, boff);
  k_scan3  <<<(N_NODES + 255) / 256, 256, 0, stream>>>(rowptr, boff);
  k_scatter<<<(N_TOT + 255) / 256, 256, 0, stream>>>(ei, flag, rowptr, fill, col);

  const int grid_t12 = (N_NODES + 31) / 32;        // 8 nodes/wave * 4 waves
  const int grid_wpn = (N_NODES * 64 + 255) / 256; // wave per node
  const int grid_w4n = ((N_NODES + 3) / 4 * 64 + 255) / 256; // 4 nodes per wave

  // ---- layer 1 ----
  k_transform1<<<grid_t12, 256, 0, stream>>>(x, W1, as1, ad1, h, es, ed);
  k_agg       <<<grid_wpn, 256, 0, stream>>>(h, es, ed, rowptr, col, b1, feat1);
  // ---- layer 2 ----
  k_transform2<<<grid_t12, 256, 0, stream>>>(feat1, W2, as2, ad2, h, es, ed);
  k_agg       <<<grid_wpn, 256, 0, stream>>>(h, es, ed, rowptr, col, b2, feat2);
  // ---- layer 3 ----
  k_transform3<<<grid_wpn, 256, 0, stream>>>(feat2, W3, as3, ad3, h3, es3, ed3);
  k_agg3      <<<grid_w4n, 256, 0, stream>>>(h3, es3, ed3, rowptr, col, b3, out);
}